// Round 3
// baseline (508.562 us; speedup 1.0000x reference)
//
#include <hip/hip_runtime.h>
#include <hip/hip_bf16.h>

#define NTOK    32768
#define DIMD    1024
#define RNK     128
#define NEXP    7
#define FULLKEY 7

using f32x4 = __attribute__((ext_vector_type(4))) float;
using s16x8 = __attribute__((ext_vector_type(8))) short;

__device__ __forceinline__ unsigned short f2bf(float f) {
    unsigned u = __float_as_uint(f);
    u += 0x7fffu + ((u >> 16) & 1u);   // RNE; inputs have no NaN
    return (unsigned short)(u >> 16);
}

__device__ __forceinline__ unsigned lra_bits(const int* __restrict__ mask) {
    unsigned bits = 0u;
#pragma unroll
    for (int i = 0; i < NEXP; ++i) {
        int m = mask[i];
        m = m < 0 ? 0 : (m > 7 ? 7 : m);
        bits |= (1u << m);
    }
    return bits;
}

// ---- merged prep: convert weights | bucket tokens | copy inactive rows ----
__global__ void prep_kernel(const float* __restrict__ x, const int* __restrict__ ridx,
                            const int* __restrict__ mask,
                            const float* __restrict__ Wd, const float* __restrict__ Wu,
                            unsigned short* __restrict__ WdB, unsigned short* __restrict__ WuB,
                            int* __restrict__ counts, int* __restrict__ bucket,
                            float* __restrict__ out) {
    const int b = blockIdx.x;
    const int tid = threadIdx.x;
    if (b < 1792) {
        const int NE = NEXP * RNK * DIMD;              // 917504
        int i = (b * 256 + tid) * 4;
        const float* src; unsigned short* dst; int off;
        if (i < NE) { src = Wd; dst = WdB; off = i; }
        else        { src = Wu; dst = WuB; off = i - NE; }
        if (off < NE) {
            float4 v = *reinterpret_cast<const float4*>(src + off);
            ushort4 o;
            o.x = f2bf(v.x); o.y = f2bf(v.y); o.z = f2bf(v.z); o.w = f2bf(v.w);
            *reinterpret_cast<ushort4*>(dst + off) = o;
        }
    } else if (b < 1920) {
        int t = (b - 1792) * 256 + tid;
        if (t < NTOK) {
            unsigned bits = lra_bits(mask);
            int k = ridx[t];
            if (k != FULLKEY && ((bits >> k) & 1u)) {
                int p = atomicAdd(&counts[k], 1);
                bucket[k * NTOK + p] = t;
            }
        }
    } else {
        unsigned bits = lra_bits(mask);
        for (int t = b - 1920; t < NTOK; t += 2048) {
            int k = ridx[t];
            bool act = (k != FULLKEY) && ((bits >> k) & 1u);
            if (!act) {
                const float4* src = reinterpret_cast<const float4*>(x + (size_t)t * DIMD);
                float4* dst = reinterpret_cast<float4*>(out + (size_t)t * DIMD);
                dst[tid] = src[tid];
            }
        }
    }
}

// ---- down: grid(128, 7), 512 thr. bx&3 = rank-quarter (32 ranks), bx>>2 = token chunk.
// Wd quarter staged once in 64KB LDS (XOR-swizzled); token loop barrier-free.
__launch_bounds__(512, 4)
__global__ void down_kernel(const float* __restrict__ x,
                            const unsigned short* __restrict__ WdB,
                            const int* __restrict__ counts,
                            const int* __restrict__ bucket,
                            unsigned short* __restrict__ downB) {
    const int e  = blockIdx.y;
    const int q  = blockIdx.x & 3;
    const int xc = blockIdx.x >> 2;
    const int n  = counts[e];
    const int tid = threadIdx.x;
    const int w = tid >> 6, l = tid & 63, l15 = l & 15, lk = l >> 4;

    __shared__ unsigned short sWd[32 * 1024];   // 64KB
    char* sb = reinterpret_cast<char*>(sWd);
    {
        const char* src = reinterpret_cast<const char*>(WdB + ((size_t)e * RNK + q * 32) * DIMD);
#pragma unroll
        for (int i = 0; i < 8; ++i) {
            const int g = (i * 512 + tid) * 16;
            const int row = g >> 11, cb = g & 2047;
            const s16x8 v = *reinterpret_cast<const s16x8*>(src + g);
            *reinterpret_cast<s16x8*>(sb + row * 2048 + (cb ^ ((row & 7) << 4))) = v;
        }
    }
    __syncthreads();

    const f32x4 zero = {0.f, 0.f, 0.f, 0.f};
    for (int tile = xc * 8 + w; tile * 16 < n; tile += 256) {
        int idx = tile * 16 + l15;
        if (idx >= n) idx = n - 1;
        const int t = bucket[e * NTOK + idx];
        const float* xr = x + (size_t)t * DIMD;

        f32x4 acc0 = zero, acc1 = zero;
#pragma unroll 2
        for (int kc = 0; kc < 8; ++kc) {
            s16x8 a[4];
#pragma unroll
            for (int ks = 0; ks < 4; ++ks) {
                const float* p = xr + kc * 128 + ks * 32 + lk * 8;
                const f32x4 v0 = *reinterpret_cast<const f32x4*>(p);
                const f32x4 v1 = *reinterpret_cast<const f32x4*>(p + 4);
                s16x8 av;
#pragma unroll
                for (int j = 0; j < 4; ++j) {
                    av[j]     = (short)f2bf(v0[j]);
                    av[4 + j] = (short)f2bf(v1[j]);
                }
                a[ks] = av;
            }
#pragma unroll
            for (int ks = 0; ks < 4; ++ks) {
                const int cb = kc * 256 + ks * 64 + lk * 16;
                const int r0 = l15, r1 = 16 + l15;
                const s16x8 b0 = *reinterpret_cast<const s16x8*>(sb + r0 * 2048 + (cb ^ ((r0 & 7) << 4)));
                const s16x8 b1 = *reinterpret_cast<const s16x8*>(sb + r1 * 2048 + (cb ^ ((r1 & 7) << 4)));
                acc0 = __builtin_amdgcn_mfma_f32_16x16x32_bf16(a[ks], b0, acc0, 0, 0, 0);
                acc1 = __builtin_amdgcn_mfma_f32_16x16x32_bf16(a[ks], b1, acc1, 0, 0, 0);
            }
        }
        int t4[4];
#pragma unroll
        for (int j = 0; j < 4; ++j) t4[j] = __shfl(t, lk * 4 + j);
#pragma unroll
        for (int j = 0; j < 4; ++j) {
            unsigned short* dr = downB + (size_t)t4[j] * RNK + q * 32;
            dr[l15]      = f2bf(acc0[j]);
            dr[16 + l15] = f2bf(acc1[j]);
        }
    }
}

// ---- up: grid(128, 7), 512 thr. bx&3 = dim-quarter (256 dims), bx>>2 = token chunk.
// Wu quarter staged once in 64KB LDS; epilogue out = x + acc.
__launch_bounds__(512, 4)
__global__ void up_kernel(const float* __restrict__ x,
                          const unsigned short* __restrict__ WuB,
                          const unsigned short* __restrict__ downB,
                          const int* __restrict__ counts,
                          const int* __restrict__ bucket,
                          float* __restrict__ out) {
    const int e  = blockIdx.y;
    const int dq = blockIdx.x & 3;
    const int xc = blockIdx.x >> 2;
    const int n  = counts[e];
    const int tid = threadIdx.x;
    const int w = tid >> 6, l = tid & 63, l15 = l & 15, lk = l >> 4;

    __shared__ unsigned short sWu[256 * 128];   // 64KB
    char* sb = reinterpret_cast<char*>(sWu);
    {
        const char* src = reinterpret_cast<const char*>(WuB + ((size_t)e * DIMD + dq * 256) * RNK);
#pragma unroll
        for (int i = 0; i < 8; ++i) {
            const int g = (i * 512 + tid) * 16;
            const int row = g >> 8, cb = g & 255;
            const s16x8 v = *reinterpret_cast<const s16x8*>(src + g);
            *reinterpret_cast<s16x8*>(sb + row * 256 + (cb ^ ((row & 7) << 4))) = v;
        }
    }
    __syncthreads();

    const f32x4 zero = {0.f, 0.f, 0.f, 0.f};
    for (int tile = xc * 8 + w; tile * 16 < n; tile += 256) {
        int idx = tile * 16 + l15;
        if (idx >= n) idx = n - 1;
        const int t = bucket[e * NTOK + idx];

        s16x8 a2[4];
#pragma unroll
        for (int ks = 0; ks < 4; ++ks)
            a2[ks] = *reinterpret_cast<const s16x8*>(downB + (size_t)t * RNK + ks * 32 + lk * 8);

        int t4[4];
#pragma unroll
        for (int j = 0; j < 4; ++j) t4[j] = __shfl(t, lk * 4 + j);

        f32x4 acc[16];
#pragma unroll
        for (int i = 0; i < 16; ++i) acc[i] = zero;

#pragma unroll
        for (int ks = 0; ks < 4; ++ks) {
            const int cb = ks * 64 + lk * 16;
#pragma unroll
            for (int nn = 0; nn < 16; ++nn) {
                const int row = nn * 16 + l15;
                const s16x8 b = *reinterpret_cast<const s16x8*>(sb + row * 256 + (cb ^ ((row & 7) << 4)));
                acc[nn] = __builtin_amdgcn_mfma_f32_16x16x32_bf16(a2[ks], b, acc[nn], 0, 0, 0);
            }
        }

#pragma unroll
        for (int nn = 0; nn < 16; ++nn) {
#pragma unroll
            for (int j = 0; j < 4; ++j) {
                const size_t off = (size_t)t4[j] * DIMD + dq * 256 + nn * 16 + l15;
                out[off] = x[off] + acc[nn][j];
            }
        }
    }
}

extern "C" void kernel_launch(void* const* d_in, const int* in_sizes, int n_in,
                              void* d_out, int out_size, void* d_ws, size_t ws_size,
                              hipStream_t stream) {
    const float* x  = (const float*)d_in[0];
    const int* ridx = (const int*)d_in[1];
    const int* mask = (const int*)d_in[2];
    const float* Wd = (const float*)d_in[3];
    const float* Wu = (const float*)d_in[4];
    float* out = (float*)d_out;

    char* ws = (char*)d_ws;
    int* counts = (int*)ws;                                    // 256 B
    int* bucket = (int*)(ws + 256);                            // 917504 B
    unsigned short* WdB   = (unsigned short*)(ws + 917760);    // 1835008 B
    unsigned short* WuB   = (unsigned short*)(ws + 2752768);   // 1835008 B
    unsigned short* downB = (unsigned short*)(ws + 4587776);   // 8388608 B (tot ~12.97 MB)

    hipMemsetAsync(counts, 0, 8 * sizeof(int), stream);
    prep_kernel<<<dim3(3968), dim3(256), 0, stream>>>(x, ridx, mask, Wd, Wu, WdB, WuB, counts, bucket, out);
    down_kernel<<<dim3(128, NEXP), dim3(512), 0, stream>>>(x, WdB, counts, bucket, downB);
    up_kernel<<<dim3(128, NEXP), dim3(512), 0, stream>>>(x, WuB, downB, counts, bucket, out);
}

// Round 4
// 217.067 us; speedup vs baseline: 2.3429x; 2.3429x over previous
//
#include <hip/hip_runtime.h>
#include <hip/hip_bf16.h>

#define NTOK    32768
#define DIMD    1024
#define RNK     128
#define NEXP    7
#define FULLKEY 7
#define NTILE   68       // grid width for expert kernels (64 tokens/tile, grid-stride)

using f32x4 = __attribute__((ext_vector_type(4))) float;
using s16x8 = __attribute__((ext_vector_type(8))) short;

__device__ __forceinline__ unsigned short f2bf(float f) {
    unsigned u = __float_as_uint(f);
    u += 0x7fffu + ((u >> 16) & 1u);   // RNE; inputs have no NaN
    return (unsigned short)(u >> 16);
}

__device__ __forceinline__ unsigned lra_bits(const int* __restrict__ mask) {
    unsigned bits = 0u;
#pragma unroll
    for (int i = 0; i < NEXP; ++i) {
        int m = mask[i];
        m = m < 0 ? 0 : (m > 7 ? 7 : m);
        bits |= (1u << m);
    }
    return bits;
}

// ---- merged prep: convert weights | bucket tokens | copy inactive rows ----
__global__ void prep_kernel(const float* __restrict__ x, const int* __restrict__ ridx,
                            const int* __restrict__ mask,
                            const float* __restrict__ Wd, const float* __restrict__ Wu,
                            unsigned short* __restrict__ WdB, unsigned short* __restrict__ WuB,
                            int* __restrict__ counts, int* __restrict__ bucket,
                            float* __restrict__ out) {
    const int b = blockIdx.x;
    const int tid = threadIdx.x;
    if (b < 1792) {
        const int NE = NEXP * RNK * DIMD;              // 917504
        int i = (b * 256 + tid) * 4;
        const float* src; unsigned short* dst; int off;
        if (i < NE) { src = Wd; dst = WdB; off = i; }
        else        { src = Wu; dst = WuB; off = i - NE; }
        if (off < NE) {
            float4 v = *reinterpret_cast<const float4*>(src + off);
            ushort4 o;
            o.x = f2bf(v.x); o.y = f2bf(v.y); o.z = f2bf(v.z); o.w = f2bf(v.w);
            *reinterpret_cast<ushort4*>(dst + off) = o;
        }
    } else if (b < 1920) {
        int t = (b - 1792) * 256 + tid;
        if (t < NTOK) {
            unsigned bits = lra_bits(mask);
            int k = ridx[t];
            if (k != FULLKEY && ((bits >> k) & 1u)) {
                int p = atomicAdd(&counts[k], 1);
                bucket[k * NTOK + p] = t;
            }
        }
    } else {
        unsigned bits = lra_bits(mask);
        for (int t = b - 1920; t < NTOK; t += 2048) {
            int k = ridx[t];
            bool act = (k != FULLKEY) && ((bits >> k) & 1u);
            if (!act) {
                const float4* src = reinterpret_cast<const float4*>(x + (size_t)t * DIMD);
                float4* dst = reinterpret_cast<float4*>(out + (size_t)t * DIMD);
                dst[tid] = src[tid];
            }
        }
    }
}

// ---- down: block = 64 tokens x 128 ranks. x tile staged once per K-half (LDS bf16),
// Wd staged in 16KB chunks. Waves: 4 token-groups x 2 rank-halves, acc[4]. ----
__launch_bounds__(512, 4)
__global__ void down_kernel(const float* __restrict__ x,
                            const unsigned short* __restrict__ WdB,
                            const int* __restrict__ counts,
                            const int* __restrict__ bucket,
                            unsigned short* __restrict__ downB) {
    const int e = blockIdx.y;
    const int n = counts[e];
    if (n <= 0) return;
    const int tid = threadIdx.x;
    const int w = tid >> 6, l = tid & 63, l15 = l & 15, lk = l >> 4;
    const int tg = w & 3, rh = w >> 2;
    const int* bkt = bucket + e * NTOK;

    __shared__ unsigned short xB[64 * 512];    // 64KB: [64 tok][512 K-half] bf16, swizzled (rowbytes 1024)
    __shared__ unsigned short sWd[128 * 64];   // 16KB: [128 r][64 K] bf16, swizzled (rowbytes 128)
    char* xb = reinterpret_cast<char*>(xB);
    char* wb = reinterpret_cast<char*>(sWd);

    const f32x4 zero = {0.f, 0.f, 0.f, 0.f};

    for (int tile = blockIdx.x; tile * 64 < n; tile += gridDim.x) {
        const int base = tile * 64;
        f32x4 acc[4];
#pragma unroll
        for (int i = 0; i < 4; ++i) acc[i] = zero;

        for (int h = 0; h < 2; ++h) {
            __syncthreads();   // protect xB/sWd from previous phase's readers
            {   // stage x half-tile: row = tid>>3, 8 threads/row, 128B-interleaved
                const int row = tid >> 3;
                int idx = base + row; if (idx >= n) idx = n - 1;
                const int t = bkt[idx];
                const float* xr = x + (size_t)t * DIMD + h * 512 + (tid & 7) * 4;
#pragma unroll
                for (int i = 0; i < 16; ++i) {
                    const f32x4 v = *reinterpret_cast<const f32x4*>(xr + i * 32);
                    ushort4 o;
                    o.x = f2bf(v[0]); o.y = f2bf(v[1]); o.z = f2bf(v[2]); o.w = f2bf(v[3]);
                    const int cb = (tid & 7) * 8 + i * 64;   // byte col
                    *reinterpret_cast<ushort4*>(xb + row * 1024 + (cb ^ ((row & 7) << 4))) = o;
                }
            }
            for (int kc = 0; kc < 8; ++kc) {
                if (kc > 0) __syncthreads();   // h-loop top barrier covers kc==0 staging hazard
                {   // stage Wd chunk [128 r][64 K]: 32B/thread
#pragma unroll
                    for (int i = 0; i < 2; ++i) {
                        const int gg = tid * 32 + i * 16;
                        const int r = gg >> 7, cb = gg & 127;
                        const s16x8 v = *reinterpret_cast<const s16x8*>(
                            WdB + (size_t)(e * RNK + r) * DIMD + h * 512 + kc * 64 + (cb >> 1));
                        *reinterpret_cast<s16x8*>(wb + r * 128 + (cb ^ ((r & 7) << 4))) = v;
                    }
                }
                __syncthreads();
#pragma unroll
                for (int ks = 0; ks < 2; ++ks) {
                    const int arow = tg * 16 + l15;
                    const int acb = kc * 128 + ks * 64 + lk * 16;
                    const s16x8 a = *reinterpret_cast<const s16x8*>(xb + arow * 1024 + (acb ^ ((arow & 7) << 4)));
#pragma unroll
                    for (int nn = 0; nn < 4; ++nn) {
                        const int brow = rh * 64 + nn * 16 + l15;
                        const int bcb = ks * 64 + lk * 16;
                        const s16x8 b = *reinterpret_cast<const s16x8*>(wb + brow * 128 + (bcb ^ ((brow & 7) << 4)));
                        acc[nn] = __builtin_amdgcn_mfma_f32_16x16x32_bf16(a, b, acc[nn], 0, 0, 0);
                    }
                }
            }
        }
        // write downB: token row = base + tg*16 + lk*4 + j, col = rh*64 + nn*16 + l15
        int t4[4];
#pragma unroll
        for (int j = 0; j < 4; ++j) {
            int idx = base + tg * 16 + lk * 4 + j; if (idx >= n) idx = n - 1;
            t4[j] = bkt[idx];
        }
#pragma unroll
        for (int nn = 0; nn < 4; ++nn) {
#pragma unroll
            for (int j = 0; j < 4; ++j) {
                downB[(size_t)t4[j] * RNK + rh * 64 + nn * 16 + l15] = f2bf(acc[nn][j]);
            }
        }
    }
}

// ---- up: block = 64 tokens x full 1024 dims (full-row writes, R1-proven traffic).
// a2 from downB once per tile; Wu staged 32KB per dc chunk. Waves: 4 tok-groups x 2 dim-halves. ----
__launch_bounds__(512, 4)
__global__ void up_kernel(const float* __restrict__ x,
                          const unsigned short* __restrict__ WuB,
                          const unsigned short* __restrict__ downB,
                          const int* __restrict__ counts,
                          const int* __restrict__ bucket,
                          float* __restrict__ out) {
    const int e = blockIdx.y;
    const int n = counts[e];
    if (n <= 0) return;
    const int tid = threadIdx.x;
    const int w = tid >> 6, l = tid & 63, l15 = l & 15, lk = l >> 4;
    const int tq = w & 3, dh = w >> 2;
    const int* bkt = bucket + e * NTOK;

    __shared__ unsigned short sWu[128 * 128];   // 32KB: [128 d][128 r] bf16, swizzled (rowbytes 256)
    char* wb = reinterpret_cast<char*>(sWu);

    const f32x4 zero = {0.f, 0.f, 0.f, 0.f};

    for (int tile = blockIdx.x; tile * 64 < n; tile += gridDim.x) {
        const int base = tile * 64;
        // A fragments: down rows for this wave's 16 tokens
        int idxA = base + tq * 16 + l15; if (idxA >= n) idxA = n - 1;
        const int tA = bkt[idxA];
        s16x8 a2[4];
#pragma unroll
        for (int ks = 0; ks < 4; ++ks)
            a2[ks] = *reinterpret_cast<const s16x8*>(downB + (size_t)tA * RNK + ks * 32 + lk * 8);

        int t4[4];
#pragma unroll
        for (int j = 0; j < 4; ++j) {
            int idx = base + tq * 16 + lk * 4 + j; if (idx >= n) idx = n - 1;
            t4[j] = bkt[idx];
        }

        for (int dc = 0; dc < 8; ++dc) {
            __syncthreads();   // previous phase's sWu readers done
            {   // stage Wu chunk [128 d][128 r]: 64B/thread
#pragma unroll
                for (int i = 0; i < 4; ++i) {
                    const int gg = tid * 64 + i * 16;
                    const int r = gg >> 8, cb = gg & 255;
                    const s16x8 v = *reinterpret_cast<const s16x8*>(
                        WuB + (size_t)(e * DIMD + dc * 128 + r) * RNK + (cb >> 1));
                    *reinterpret_cast<s16x8*>(wb + r * 256 + (cb ^ ((r & 7) << 4))) = v;
                }
            }
            __syncthreads();
            f32x4 acc[4];
#pragma unroll
            for (int i = 0; i < 4; ++i) acc[i] = zero;
#pragma unroll
            for (int ks = 0; ks < 4; ++ks) {
#pragma unroll
                for (int nn = 0; nn < 4; ++nn) {
                    const int brow = dh * 64 + nn * 16 + l15;
                    const int bcb = ks * 64 + lk * 16;
                    const s16x8 b = *reinterpret_cast<const s16x8*>(wb + brow * 256 + (bcb ^ ((brow & 7) << 4)));
                    acc[nn] = __builtin_amdgcn_mfma_f32_16x16x32_bf16(a2[ks], b, acc[nn], 0, 0, 0);
                }
            }
            // epilogue: full-row pattern — block covers the whole 128-dim chunk via 2 dh waves
#pragma unroll
            for (int nn = 0; nn < 4; ++nn) {
#pragma unroll
                for (int j = 0; j < 4; ++j) {
                    const size_t off = (size_t)t4[j] * DIMD + dc * 128 + dh * 64 + nn * 16 + l15;
                    out[off] = x[off] + acc[nn][j];
                }
            }
        }
        __syncthreads();   // sWu readers done before next tile's staging
    }
}

extern "C" void kernel_launch(void* const* d_in, const int* in_sizes, int n_in,
                              void* d_out, int out_size, void* d_ws, size_t ws_size,
                              hipStream_t stream) {
    const float* x  = (const float*)d_in[0];
    const int* ridx = (const int*)d_in[1];
    const int* mask = (const int*)d_in[2];
    const float* Wd = (const float*)d_in[3];
    const float* Wu = (const float*)d_in[4];
    float* out = (float*)d_out;

    char* ws = (char*)d_ws;
    int* counts = (int*)ws;                                    // 256 B
    int* bucket = (int*)(ws + 256);                            // 917504 B
    unsigned short* WdB   = (unsigned short*)(ws + 917760);    // 1835008 B
    unsigned short* WuB   = (unsigned short*)(ws + 2752768);   // 1835008 B
    unsigned short* downB = (unsigned short*)(ws + 4587776);   // 8388608 B (tot ~12.97 MB)

    hipMemsetAsync(counts, 0, 8 * sizeof(int), stream);
    prep_kernel<<<dim3(3968), dim3(256), 0, stream>>>(x, ridx, mask, Wd, Wu, WdB, WuB, counts, bucket, out);
    down_kernel<<<dim3(NTILE, NEXP), dim3(512), 0, stream>>>(x, WdB, counts, bucket, downB);
    up_kernel<<<dim3(NTILE, NEXP), dim3(512), 0, stream>>>(x, WuB, downB, counts, bucket, out);
}

// Round 5
// 103.536 us; speedup vs baseline: 4.9120x; 2.0965x over previous
//
#include <hip/hip_runtime.h>
#include <hip/hip_bf16.h>

#define NTOK    32768
#define DIMD    1024
#define RNK     128
#define NEXP    7
#define FULLKEY 7
#define NTILE   68       // grid width for expert kernels (64 tokens/tile, grid-stride)

using f32x4 = __attribute__((ext_vector_type(4))) float;
using s16x8 = __attribute__((ext_vector_type(8))) short;

__device__ __forceinline__ unsigned short f2bf(float f) {
    unsigned u = __float_as_uint(f);
    u += 0x7fffu + ((u >> 16) & 1u);   // RNE; inputs have no NaN
    return (unsigned short)(u >> 16);
}

__device__ __forceinline__ unsigned lra_bits(const int* __restrict__ mask) {
    unsigned bits = 0u;
#pragma unroll
    for (int i = 0; i < NEXP; ++i) {
        int m = mask[i];
        m = m < 0 ? 0 : (m > 7 ? 7 : m);
        bits |= (1u << m);
    }
    return bits;
}

// ---- merged prep: convert weights | bucket tokens (block-aggregated atomics) | copy inactive ----
__global__ void prep_kernel(const float* __restrict__ x, const int* __restrict__ ridx,
                            const int* __restrict__ mask,
                            const float* __restrict__ Wd, const float* __restrict__ Wu,
                            unsigned short* __restrict__ WdB, unsigned short* __restrict__ WuB,
                            int* __restrict__ counts, int* __restrict__ bucket,
                            float* __restrict__ out) {
    const int b = blockIdx.x;
    const int tid = threadIdx.x;
    if (b < 1792) {
        const int NE = NEXP * RNK * DIMD;              // 917504
        int i = (b * 256 + tid) * 4;
        const float* src; unsigned short* dst; int off;
        if (i < NE) { src = Wd; dst = WdB; off = i; }
        else        { src = Wu; dst = WuB; off = i - NE; }
        if (off < NE) {
            float4 v = *reinterpret_cast<const float4*>(src + off);
            ushort4 o;
            o.x = f2bf(v.x); o.y = f2bf(v.y); o.z = f2bf(v.z); o.w = f2bf(v.w);
            *reinterpret_cast<ushort4*>(dst + off) = o;
        }
    } else if (b < 1920) {
        // bucket tokens: LDS-aggregated -> 7 global atomics per block (was 28672 total)
        __shared__ int lcnt[8];
        __shared__ int lbase[8];
        if (tid < 8) lcnt[tid] = 0;
        __syncthreads();
        const int t = (b - 1792) * 256 + tid;
        const unsigned bits = lra_bits(mask);
        const int k = ridx[t];
        const bool act = (k != FULLKEY) && ((bits >> k) & 1u);
        int pos = -1;
        if (act) pos = atomicAdd(&lcnt[k], 1);          // LDS atomic
        __syncthreads();
        if (tid < 8 && lcnt[tid] > 0) lbase[tid] = atomicAdd(&counts[tid], lcnt[tid]);
        __syncthreads();
        if (act) bucket[k * NTOK + lbase[k] + pos] = t;
    } else {
        unsigned bits = lra_bits(mask);
        for (int t = b - 1920; t < NTOK; t += 2048) {
            int k = ridx[t];
            bool act = (k != FULLKEY) && ((bits >> k) & 1u);
            if (!act) {
                const float4* src = reinterpret_cast<const float4*>(x + (size_t)t * DIMD);
                float4* dst = reinterpret_cast<float4*>(out + (size_t)t * DIMD);
                dst[tid] = src[tid];
            }
        }
    }
}

// ---- down: block = 64 tokens x 128 ranks. x tile staged once per K-half (LDS bf16),
// Wd staged in 16KB chunks. Waves: 4 token-groups x 2 rank-halves, acc[4]. ----
__launch_bounds__(512, 4)
__global__ void down_kernel(const float* __restrict__ x,
                            const unsigned short* __restrict__ WdB,
                            const int* __restrict__ counts,
                            const int* __restrict__ bucket,
                            unsigned short* __restrict__ downB) {
    const int e = blockIdx.y;
    const int n = counts[e];
    if (n <= 0) return;
    const int tid = threadIdx.x;
    const int w = tid >> 6, l = tid & 63, l15 = l & 15, lk = l >> 4;
    const int tg = w & 3, rh = w >> 2;
    const int* bkt = bucket + e * NTOK;

    __shared__ unsigned short xB[64 * 512];    // 64KB: [64 tok][512 K-half] bf16, swizzled (rowbytes 1024)
    __shared__ unsigned short sWd[128 * 64];   // 16KB: [128 r][64 K] bf16, swizzled (rowbytes 128)
    char* xb = reinterpret_cast<char*>(xB);
    char* wb = reinterpret_cast<char*>(sWd);

    const f32x4 zero = {0.f, 0.f, 0.f, 0.f};

    for (int tile = blockIdx.x; tile * 64 < n; tile += gridDim.x) {
        const int base = tile * 64;
        f32x4 acc[4];
#pragma unroll
        for (int i = 0; i < 4; ++i) acc[i] = zero;

        for (int h = 0; h < 2; ++h) {
            __syncthreads();   // protect xB/sWd from previous phase's readers
            {   // stage x half-tile: row = tid>>3, 8 threads/row, 128B-interleaved
                const int row = tid >> 3;
                int idx = base + row; if (idx >= n) idx = n - 1;
                const int t = bkt[idx];
                const float* xr = x + (size_t)t * DIMD + h * 512 + (tid & 7) * 4;
#pragma unroll
                for (int i = 0; i < 16; ++i) {
                    const f32x4 v = *reinterpret_cast<const f32x4*>(xr + i * 32);
                    ushort4 o;
                    o.x = f2bf(v[0]); o.y = f2bf(v[1]); o.z = f2bf(v[2]); o.w = f2bf(v[3]);
                    const int cb = (tid & 7) * 8 + i * 64;   // byte col
                    *reinterpret_cast<ushort4*>(xb + row * 1024 + (cb ^ ((row & 7) << 4))) = o;
                }
            }
            for (int kc = 0; kc < 8; ++kc) {
                if (kc > 0) __syncthreads();   // h-loop top barrier covers kc==0 staging hazard
                {   // stage Wd chunk [128 r][64 K]: 32B/thread
#pragma unroll
                    for (int i = 0; i < 2; ++i) {
                        const int gg = tid * 32 + i * 16;
                        const int r = gg >> 7, cb = gg & 127;
                        const s16x8 v = *reinterpret_cast<const s16x8*>(
                            WdB + (size_t)(e * RNK + r) * DIMD + h * 512 + kc * 64 + (cb >> 1));
                        *reinterpret_cast<s16x8*>(wb + r * 128 + (cb ^ ((r & 7) << 4))) = v;
                    }
                }
                __syncthreads();
#pragma unroll
                for (int ks = 0; ks < 2; ++ks) {
                    const int arow = tg * 16 + l15;
                    const int acb = kc * 128 + ks * 64 + lk * 16;
                    const s16x8 a = *reinterpret_cast<const s16x8*>(xb + arow * 1024 + (acb ^ ((arow & 7) << 4)));
#pragma unroll
                    for (int nn = 0; nn < 4; ++nn) {
                        const int brow = rh * 64 + nn * 16 + l15;
                        const int bcb = ks * 64 + lk * 16;
                        const s16x8 b = *reinterpret_cast<const s16x8*>(wb + brow * 128 + (bcb ^ ((brow & 7) << 4)));
                        acc[nn] = __builtin_amdgcn_mfma_f32_16x16x32_bf16(a, b, acc[nn], 0, 0, 0);
                    }
                }
            }
        }
        // write downB: token row = base + tg*16 + lk*4 + j, col = rh*64 + nn*16 + l15
        int t4[4];
#pragma unroll
        for (int j = 0; j < 4; ++j) {
            int idx = base + tg * 16 + lk * 4 + j; if (idx >= n) idx = n - 1;
            t4[j] = bkt[idx];
        }
#pragma unroll
        for (int nn = 0; nn < 4; ++nn) {
#pragma unroll
            for (int j = 0; j < 4; ++j) {
                downB[(size_t)t4[j] * RNK + rh * 64 + nn * 16 + l15] = f2bf(acc[nn][j]);
            }
        }
    }
}

// ---- up: block = 64 tokens x full 1024 dims (full-row writes).
// a2 from downB once per tile; Wu staged 32KB per dc chunk. Waves: 4 tok-groups x 2 dim-halves. ----
__launch_bounds__(512, 4)
__global__ void up_kernel(const float* __restrict__ x,
                          const unsigned short* __restrict__ WuB,
                          const unsigned short* __restrict__ downB,
                          const int* __restrict__ counts,
                          const int* __restrict__ bucket,
                          float* __restrict__ out) {
    const int e = blockIdx.y;
    const int n = counts[e];
    if (n <= 0) return;
    const int tid = threadIdx.x;
    const int w = tid >> 6, l = tid & 63, l15 = l & 15, lk = l >> 4;
    const int tq = w & 3, dh = w >> 2;
    const int* bkt = bucket + e * NTOK;

    __shared__ unsigned short sWu[128 * 128];   // 32KB: [128 d][128 r] bf16, swizzled (rowbytes 256)
    char* wb = reinterpret_cast<char*>(sWu);

    const f32x4 zero = {0.f, 0.f, 0.f, 0.f};

    for (int tile = blockIdx.x; tile * 64 < n; tile += gridDim.x) {
        const int base = tile * 64;
        // A fragments: down rows for this wave's 16 tokens
        int idxA = base + tq * 16 + l15; if (idxA >= n) idxA = n - 1;
        const int tA = bkt[idxA];
        s16x8 a2[4];
#pragma unroll
        for (int ks = 0; ks < 4; ++ks)
            a2[ks] = *reinterpret_cast<const s16x8*>(downB + (size_t)tA * RNK + ks * 32 + lk * 8);

        int t4[4];
#pragma unroll
        for (int j = 0; j < 4; ++j) {
            int idx = base + tq * 16 + lk * 4 + j; if (idx >= n) idx = n - 1;
            t4[j] = bkt[idx];
        }

        for (int dc = 0; dc < 8; ++dc) {
            __syncthreads();   // previous phase's sWu readers done
            {   // stage Wu chunk [128 d][128 r]: 64B/thread
#pragma unroll
                for (int i = 0; i < 4; ++i) {
                    const int gg = tid * 64 + i * 16;
                    const int r = gg >> 8, cb = gg & 255;
                    const s16x8 v = *reinterpret_cast<const s16x8*>(
                        WuB + (size_t)(e * DIMD + dc * 128 + r) * RNK + (cb >> 1));
                    *reinterpret_cast<s16x8*>(wb + r * 256 + (cb ^ ((r & 7) << 4))) = v;
                }
            }
            __syncthreads();
            f32x4 acc[4];
#pragma unroll
            for (int i = 0; i < 4; ++i) acc[i] = zero;
#pragma unroll
            for (int ks = 0; ks < 4; ++ks) {
#pragma unroll
                for (int nn = 0; nn < 4; ++nn) {
                    const int brow = dh * 64 + nn * 16 + l15;
                    const int bcb = ks * 64 + lk * 16;
                    const s16x8 b = *reinterpret_cast<const s16x8*>(wb + brow * 256 + (bcb ^ ((brow & 7) << 4)));
                    acc[nn] = __builtin_amdgcn_mfma_f32_16x16x32_bf16(a2[ks], b, acc[nn], 0, 0, 0);
                }
            }
            // epilogue: full-row pattern — block covers the whole 128-dim chunk via 2 dh waves
#pragma unroll
            for (int nn = 0; nn < 4; ++nn) {
#pragma unroll
                for (int j = 0; j < 4; ++j) {
                    const size_t off = (size_t)t4[j] * DIMD + dc * 128 + dh * 64 + nn * 16 + l15;
                    out[off] = x[off] + acc[nn][j];
                }
            }
        }
        __syncthreads();   // sWu readers done before next tile's staging
    }
}

extern "C" void kernel_launch(void* const* d_in, const int* in_sizes, int n_in,
                              void* d_out, int out_size, void* d_ws, size_t ws_size,
                              hipStream_t stream) {
    const float* x  = (const float*)d_in[0];
    const int* ridx = (const int*)d_in[1];
    const int* mask = (const int*)d_in[2];
    const float* Wd = (const float*)d_in[3];
    const float* Wu = (const float*)d_in[4];
    float* out = (float*)d_out;

    char* ws = (char*)d_ws;
    int* counts = (int*)ws;                                    // 256 B
    int* bucket = (int*)(ws + 256);                            // 917504 B
    unsigned short* WdB   = (unsigned short*)(ws + 917760);    // 1835008 B
    unsigned short* WuB   = (unsigned short*)(ws + 2752768);   // 1835008 B
    unsigned short* downB = (unsigned short*)(ws + 4587776);   // 8388608 B (tot ~12.97 MB)

    hipMemsetAsync(counts, 0, 8 * sizeof(int), stream);
    prep_kernel<<<dim3(3968), dim3(256), 0, stream>>>(x, ridx, mask, Wd, Wu, WdB, WuB, counts, bucket, out);
    down_kernel<<<dim3(NTILE, NEXP), dim3(512), 0, stream>>>(x, WdB, counts, bucket, downB);
    up_kernel<<<dim3(NTILE, NEXP), dim3(512), 0, stream>>>(x, WuB, downB, counts, bucket, out);
}